// Round 12
// baseline (214.257 us; speedup 1.0000x reference)
//
#include <hip/hip_runtime.h>
#include <hip/hip_bf16.h>
#include <float.h>

#define N_NODES  50000
#define N_EDGES  640000
#define N_GRAPHS 128
#define DIM      128
#define CAP      64        // bucket slots per node; P(deg>=64) ~ 1e-24 per node
#define ZROW     N_NODES   // index of the all-zero row (per quarter)
#define NROWS    (N_NODES+1)
#define NSLICE   8
#define SLICE_W  6250
#define NCHUNK   256
#define CHUNK_E  2500
#define GEMM_BLKS 512
#define POOL_BLKS 1024     // 8 per graph
#define AGG_CHUNKS 782     // ceil(50000/64)
#define AGG_BLKS  (8*391)  // 8 xcd-slots x 391 -> chunk=(bid>>3)*2+(bid&1) in [0,782)

typedef __attribute__((ext_vector_type(8))) short bf16x8;
typedef __attribute__((ext_vector_type(4))) float f32x4;

__device__ __forceinline__ unsigned short f2bf(float f){
  unsigned int u = __float_as_uint(f);
  u += 0x7fffu + ((u >> 16) & 1u);     // round-to-nearest-even
  return (unsigned short)(u >> 16);
}
__device__ __forceinline__ float2 up2(unsigned int p){
  return make_float2(__uint_as_float(p << 16),
                     __uint_as_float(p & 0xffff0000u));
}

// zero cnt + the 4 quarter-zero-rows of both feature buffers
__global__ __launch_bounds__(256) void zero_misc(int* __restrict__ cnt,
    unsigned int* __restrict__ z0, unsigned int* __restrict__ z1){
  int i = blockIdx.x*256 + threadIdx.x;
  if (i < N_NODES) cnt[i] = 0;
  else if (i < N_NODES + 128){
    int j = i - N_NODES;
    unsigned int* z = (j < 64) ? z0 : z1;
    int jj = j & 63;
    int q = jj >> 4, k = jj & 15;
    z[((size_t)q*NROWS + ZROW)*16 + k] = 0;
  }
}

// XCD-sliced scatter (L2-locality heuristic only; correctness order-free)
__global__ __launch_bounds__(256) void scatter_sliced(
    const int* __restrict__ ei, int* __restrict__ cnt, int* __restrict__ srcb){
  int slice = blockIdx.x & (NSLICE-1);
  int chunk = blockIdx.x >> 3;
  int e0 = chunk * CHUNK_E;
  for (int e = e0 + threadIdx.x; e < e0 + CHUNK_E; e += 256){
    int c = ei[N_EDGES + e];
    if (c / SLICE_W == slice){
      int r = ei[e];
      int pos = atomicAdd(&cnt[c], 1);
      srcb[(c << 6) + pos] = r;
    }
  }
}

// merged: make_dis + graph_starts + w3_to_bf16
__global__ __launch_bounds__(256) void prep(
    const int* __restrict__ cnt, float* __restrict__ dis,
    const int* __restrict__ batch, int* __restrict__ gs,
    const float* __restrict__ w0, const float* __restrict__ w1,
    const float* __restrict__ w2, unsigned int* __restrict__ o0,
    unsigned int* __restrict__ o1, unsigned int* __restrict__ o2){
  int b = blockIdx.x, tid = threadIdx.x;
  if (b < 196){
    int i = b*256 + tid;
    if (i < N_NODES){
      dis[i] = 1.0f / sqrtf((float)(cnt[i] + 1));
      int bb = batch[i];
      int bp = (i == 0) ? -1 : batch[i-1];
      for (int g = bp + 1; g <= bb; ++g) gs[g] = i;
      if (i == N_NODES - 1)
        for (int g = bb + 1; g <= N_GRAPHS; ++g) gs[g] = N_NODES;
    }
  } else {
    int i = (b - 196)*256 + tid;
    if (i < 3*8192){
      int a = i >> 13, j = i & 8191;
      const float* src = (a == 0) ? w0 : (a == 1) ? w1 : w2;
      unsigned int* dst = (a == 0) ? o0 : (a == 1) ? o1 : o2;
      float2 v = ((const float2*)src)[j];
      dst[j] = (unsigned int)f2bf(v.x) | ((unsigned int)f2bf(v.y) << 16);
    }
  }
}

// ---- GEMM body (bf16 quarter-major input), dis-scaled quarter-major output ----
__device__ __forceinline__ void gemm_body_bf(int wid,
    const unsigned short* __restrict__ A, const unsigned short* __restrict__ Wb,
    const float* __restrict__ bias, const float* __restrict__ dis,
    unsigned short* __restrict__ C, int total_waves){
  int lane = threadIdx.x & 63;
  int l15 = lane & 15, l4 = lane >> 4;
  bf16x8 wf[8][4];
  #pragma unroll
  for (int ob = 0; ob < 8; ++ob)
    #pragma unroll
    for (int ks = 0; ks < 4; ++ks)
      wf[ob][ks] = *(const bf16x8*)&Wb[(ob*16 + l15)*128 + ks*32 + l4*8];
  float bv[8];
  #pragma unroll
  for (int ob = 0; ob < 8; ++ob) bv[ob] = bias[ob*16 + l15];
  for (int t = wid; t < N_NODES/16; t += total_waves){
    int row0 = t*16;
    bf16x8 af[4];
    #pragma unroll
    for (int ks = 0; ks < 4; ++ks)
      af[ks] = *(const bf16x8*)&A[((size_t)ks*NROWS + row0 + l15)*32 + l4*8];
    f32x4 acc[8];
    #pragma unroll
    for (int ob = 0; ob < 8; ++ob) acc[ob] = (f32x4){0.f,0.f,0.f,0.f};
    #pragma unroll
    for (int ks = 0; ks < 4; ++ks)
      #pragma unroll
      for (int ob = 0; ob < 8; ++ob)
        acc[ob] = __builtin_amdgcn_mfma_f32_16x16x32_bf16(af[ks], wf[ob][ks],
                                                          acc[ob], 0, 0, 0);
    float dv[4];
    #pragma unroll
    for (int r = 0; r < 4; ++r) dv[r] = dis[row0 + l4*4 + r];
    #pragma unroll
    for (int ob = 0; ob < 8; ++ob)
      #pragma unroll
      for (int r = 0; r < 4; ++r)
        C[((size_t)(ob>>1)*NROWS + row0 + l4*4 + r)*32 + (ob&1)*16 + l15] =
            f2bf((acc[ob][r] + bv[ob]) * dv[r]);
  }
}

// layer-0 GEMM: f32 input (row-major), quarter-major output
__global__ __launch_bounds__(256, 2) void gemm_f32(
    const float* __restrict__ A, const unsigned short* __restrict__ Wb,
    const float* __restrict__ bias, const float* __restrict__ dis,
    unsigned short* __restrict__ C, int total_waves){
  int lane = threadIdx.x & 63;
  int wid = blockIdx.x*4 + (threadIdx.x >> 6);
  int l15 = lane & 15, l4 = lane >> 4;
  bf16x8 wf[8][4];
  #pragma unroll
  for (int ob = 0; ob < 8; ++ob)
    #pragma unroll
    for (int ks = 0; ks < 4; ++ks)
      wf[ob][ks] = *(const bf16x8*)&Wb[(ob*16 + l15)*128 + ks*32 + l4*8];
  float bv[8];
  #pragma unroll
  for (int ob = 0; ob < 8; ++ob) bv[ob] = bias[ob*16 + l15];
  for (int t = wid; t < N_NODES/16; t += total_waves){
    int row0 = t*16;
    bf16x8 af[4];
    #pragma unroll
    for (int ks = 0; ks < 4; ++ks){
      const float4* ap = (const float4*)&A[(size_t)(row0 + l15)*128 + ks*32 + l4*8];
      float4 fa = ap[0], fb = ap[1];
      bf16x8 v;
      v[0]=(short)f2bf(fa.x); v[1]=(short)f2bf(fa.y);
      v[2]=(short)f2bf(fa.z); v[3]=(short)f2bf(fa.w);
      v[4]=(short)f2bf(fb.x); v[5]=(short)f2bf(fb.y);
      v[6]=(short)f2bf(fb.z); v[7]=(short)f2bf(fb.w);
      af[ks] = v;
    }
    f32x4 acc[8];
    #pragma unroll
    for (int ob = 0; ob < 8; ++ob) acc[ob] = (f32x4){0.f,0.f,0.f,0.f};
    #pragma unroll
    for (int ks = 0; ks < 4; ++ks)
      #pragma unroll
      for (int ob = 0; ob < 8; ++ob)
        acc[ob] = __builtin_amdgcn_mfma_f32_16x16x32_bf16(af[ks], wf[ob][ks],
                                                          acc[ob], 0, 0, 0);
    float dv[4];
    #pragma unroll
    for (int r = 0; r < 4; ++r) dv[r] = dis[row0 + l4*4 + r];
    #pragma unroll
    for (int ob = 0; ob < 8; ++ob)
      #pragma unroll
      for (int r = 0; r < 4; ++r)
        C[((size_t)(ob>>1)*NROWS + row0 + l4*4 + r)*32 + (ob&1)*16 + l15] =
            f2bf((acc[ob][r] + bv[ob]) * dv[r]);
  }
}

// quarter-pass aggregate: 4-lane group per node-quarter, 16 nodes/wave.
// quarter q pinned to an XCD pair via q=(bid&7)>>1 (L2-residency heuristic).
// out_q[c] = relu(dis[c]*(xw_q[c] + sum_in xw_q[r])); gate partial to gq[q][c].
__global__ __launch_bounds__(256) void aggregate_q(
    const uint4* __restrict__ xq,       // [4][NROWS][4] uint4
    const int* __restrict__ cnt, const int* __restrict__ srcb,
    const float* __restrict__ dis,
    uint4* __restrict__ xoq, const float* __restrict__ gw,
    float* __restrict__ gq){
  int tid  = threadIdx.x;
  int lane = tid & 63;
  int wv   = tid >> 6;
  int grp  = lane >> 2, l4 = lane & 3;
  int q     = (blockIdx.x & 7) >> 1;
  int chunk = (blockIdx.x >> 3)*2 + (blockIdx.x & 1);   // 0..781
  int node0 = chunk*64 + wv*16 + grp;
  bool valid = node0 < N_NODES;
  int node  = valid ? node0 : 0;
  int n     = valid ? cnt[node] : 0;
  int base  = node << 6;
  size_t qbase = (size_t)q*NROWS*4;
  uint4 v = xq[qbase + (size_t)node*4 + l4];
  float acc[8];
  {
    float2 a0 = up2(v.x), a1 = up2(v.y), a2 = up2(v.z), a3 = up2(v.w);
    acc[0]=a0.x; acc[1]=a0.y; acc[2]=a1.x; acc[3]=a1.y;
    acc[4]=a2.x; acc[5]=a2.y; acc[6]=a3.x; acc[7]=a3.y;
  }
  for (int e = 0; e < n; e += 8){
    int4 sa = *(const int4*)&srcb[base + e];
    int4 sb = *(const int4*)&srcb[base + e + 4];
    int r0 = (e   < n) ? sa.x : ZROW;
    int r1 = (e+1 < n) ? sa.y : ZROW;
    int r2 = (e+2 < n) ? sa.z : ZROW;
    int r3 = (e+3 < n) ? sa.w : ZROW;
    int r4 = (e+4 < n) ? sb.x : ZROW;
    int r5 = (e+5 < n) ? sb.y : ZROW;
    int r6 = (e+6 < n) ? sb.z : ZROW;
    int r7 = (e+7 < n) ? sb.w : ZROW;
    uint4 u0 = xq[qbase + (size_t)r0*4 + l4];
    uint4 u1 = xq[qbase + (size_t)r1*4 + l4];
    uint4 u2 = xq[qbase + (size_t)r2*4 + l4];
    uint4 u3 = xq[qbase + (size_t)r3*4 + l4];
    uint4 u4 = xq[qbase + (size_t)r4*4 + l4];
    uint4 u5 = xq[qbase + (size_t)r5*4 + l4];
    uint4 u6 = xq[qbase + (size_t)r6*4 + l4];
    uint4 u7 = xq[qbase + (size_t)r7*4 + l4];
    #define ACC8(U) { \
      float2 b0=up2(U.x), b1=up2(U.y), b2=up2(U.z), b3=up2(U.w); \
      acc[0]+=b0.x; acc[1]+=b0.y; acc[2]+=b1.x; acc[3]+=b1.y;    \
      acc[4]+=b2.x; acc[5]+=b2.y; acc[6]+=b3.x; acc[7]+=b3.y; }
    ACC8(u0) ACC8(u1) ACC8(u2) ACC8(u3)
    ACC8(u4) ACC8(u5) ACC8(u6) ACC8(u7)
    #undef ACC8
  }
  if (valid){
    float d = dis[node];
    #pragma unroll
    for (int i = 0; i < 8; ++i) acc[i] = fmaxf(d*acc[i], 0.f);
    uint4 o;
    o.x = (unsigned int)f2bf(acc[0]) | ((unsigned int)f2bf(acc[1]) << 16);
    o.y = (unsigned int)f2bf(acc[2]) | ((unsigned int)f2bf(acc[3]) << 16);
    o.z = (unsigned int)f2bf(acc[4]) | ((unsigned int)f2bf(acc[5]) << 16);
    o.w = (unsigned int)f2bf(acc[6]) | ((unsigned int)f2bf(acc[7]) << 16);
    xoq[qbase + (size_t)node*4 + l4] = o;
    const float4* gw4 = (const float4*)gw;
    float4 g0 = gw4[q*8 + l4*2], g1 = gw4[q*8 + l4*2 + 1];
    float p = acc[0]*g0.x + acc[1]*g0.y + acc[2]*g0.z + acc[3]*g0.w
            + acc[4]*g1.x + acc[5]*g1.y + acc[6]*g1.z + acc[7]*g1.w;
    p += __shfl_xor(p, 1, 64);
    p += __shfl_xor(p, 2, 64);
    if (l4 == 0) gq[(size_t)q*N_NODES + node] = p;
  }
}

// ---- pooling body: gate = sum of 4 quarter partials + gb ----
__device__ __forceinline__ float gate_at(const float* __restrict__ gq, int i,
                                         float gbv){
  return gq[i] + gq[N_NODES + i] + gq[2*N_NODES + i] + gq[3*N_NODES + i] + gbv;
}

__device__ __forceinline__ void pool_body(int pbid,
    const unsigned int* __restrict__ x, const float* __restrict__ gq,
    float gbv, const int* __restrict__ gs, float* __restrict__ hgp,
    float* __restrict__ ssum){
  int g = pbid >> 3, q = pbid & 7, tid = threadIdx.x;
  int s = gs[g], e = gs[g+1];
  __shared__ float red[256];
  __shared__ float2 red2[4][64];
  float m = -FLT_MAX;
  for (int i = s + tid; i < e; i += 256) m = fmaxf(m, gate_at(gq, i, gbv));
  red[tid] = m; __syncthreads();
  for (int st = 128; st > 0; st >>= 1){
    if (tid < st) red[tid] = fmaxf(red[tid], red[tid+st]);
    __syncthreads();
  }
  m = red[0]; __syncthreads();
  float p = 0.f;
  for (int i = s + tid; i < e; i += 256) p += __expf(gate_at(gq, i, gbv) - m);
  red[tid] = p; __syncthreads();
  for (int st = 128; st > 0; st >>= 1){
    if (tid < st) red[tid] += red[tid+st];
    __syncthreads();
  }
  if (tid == 0 && q == 0) ssum[g] = red[0];
  int d2 = tid & 63, rg = tid >> 6;
  int qf = d2 >> 4, jf = d2 & 15;
  size_t fbase = ((size_t)qf*NROWS)*16 + jf;
  float ax = 0.f, ay = 0.f;
  for (int i = s + q*4 + rg; i < e; i += 32){
    float a = __expf(gate_at(gq, i, gbv) - m);
    float2 u = up2(x[fbase + (size_t)i*16]);
    ax += a*u.x; ay += a*u.y;
  }
  red2[rg][d2] = make_float2(ax, ay);
  __syncthreads();
  if (tid < 64){
    float2 r0 = red2[0][tid], r1 = red2[1][tid],
           r2 = red2[2][tid], r3 = red2[3][tid];
    hgp[(size_t)pbid*128 + 2*tid    ] = r0.x + r1.x + r2.x + r3.x;
    hgp[(size_t)pbid*128 + 2*tid + 1] = r0.y + r1.y + r2.y + r3.y;
  }
}

// fused: blocks [0,GEMM_BLKS) = next-layer GEMM; rest = this-layer pooling.
__global__ __launch_bounds__(256, 2) void pool_gemm(
    const unsigned int* __restrict__ xb, const float* __restrict__ gq,
    const float* __restrict__ gb, const int* __restrict__ gs,
    float* __restrict__ hgp, float* __restrict__ ssum,
    const unsigned short* __restrict__ Wb, const float* __restrict__ bias,
    const float* __restrict__ dis, unsigned short* __restrict__ xwout){
  if (blockIdx.x < GEMM_BLKS){
    int wid = blockIdx.x*4 + (threadIdx.x >> 6);
    gemm_body_bf(wid, (const unsigned short*)xb, Wb, bias, dis, xwout,
                 GEMM_BLKS*4);
  } else {
    pool_body(blockIdx.x - GEMM_BLKS, xb, gq, gb[0], gs, hgp, ssum);
  }
}

// standalone pooling (last layer)
__global__ __launch_bounds__(256) void att_pool(
    const unsigned int* __restrict__ xb, const float* __restrict__ gq,
    const float* __restrict__ gb, const int* __restrict__ gs,
    float* __restrict__ hgp, float* __restrict__ ssum){
  pool_body(blockIdx.x, xb, gq, gb[0], gs, hgp, ssum);
}

// hg[g] = sum_L (sum_q hgp[L][8g+q]) / ssum[L][g]; then MLP head
__global__ __launch_bounds__(256) void head(const float* __restrict__ hgp,
    const float* __restrict__ ssum,
    const float* __restrict__ lw, const float* __restrict__ lb,
    const float* __restrict__ cw, const float* __restrict__ cb,
    float* __restrict__ out){
  int g = blockIdx.x, tid = threadIdx.x;
  __shared__ float h[128];
  __shared__ float t1[256];
  __shared__ float red[256];
  if (tid < 128){
    float hv = 0.f;
    #pragma unroll
    for (int L = 0; L < 3; ++L){
      const float* hb = hgp + (size_t)(L*POOL_BLKS + 8*g)*128;
      float pp = 0.f;
      #pragma unroll
      for (int q = 0; q < 8; ++q) pp += hb[q*128 + tid];
      float sv = ssum[L*N_GRAPHS + g];
      hv += (sv > 0.f) ? pp/sv : 0.f;
    }
    h[tid] = hv;
  }
  __syncthreads();
  const float* wr = lw + tid*128;
  float a = 0.f;
  for (int k = 0; k < 128; ++k) a += h[k]*wr[k];
  a = fmaxf(a + lb[tid], 0.f);
  t1[tid] = a;
  __syncthreads();
  int o = tid >> 7, j = tid & 127;
  float p = t1[j]*cw[o*256 + j] + t1[j+128]*cw[o*256 + j + 128];
  red[tid] = p; __syncthreads();
  for (int st = 64; st > 0; st >>= 1){
    if (j < st) red[tid] += red[tid+st];
    __syncthreads();
  }
  if (j == 0) out[g*2 + o] = red[tid] + cb[o];
}

extern "C" void kernel_launch(void* const* d_in, const int* in_sizes, int n_in,
                              void* d_out, int out_size, void* d_ws, size_t ws_size,
                              hipStream_t stream){
  const float* x   = (const float*)d_in[0];
  const int*   ei  = (const int*)d_in[1];
  const int* batch = (const int*)d_in[2];
  const float* w0  = (const float*)d_in[3];
  const float* b0  = (const float*)d_in[4];
  const float* w1  = (const float*)d_in[5];
  const float* b1  = (const float*)d_in[6];
  const float* w2  = (const float*)d_in[7];
  const float* b2  = (const float*)d_in[8];
  const float* gw  = (const float*)d_in[9];
  const float* gb  = (const float*)d_in[10];
  const float* lw  = (const float*)d_in[11];
  const float* lb  = (const float*)d_in[12];
  const float* cw  = (const float*)d_in[13];
  const float* cb  = (const float*)d_in[14];
  float* out = (float*)d_out;
  (void)in_sizes; (void)n_in; (void)out_size; (void)ws_size;

  char* ws = (char*)d_ws;
  size_t off = 0;
  auto alloc = [&](size_t bytes)->char*{
    char* p = ws + off;
    off = (off + bytes + 255) & ~(size_t)255;
    return p;
  };
  float* dis    = (float*)alloc((size_t)N_NODES*4);
  unsigned int* xw   = (unsigned int*)alloc((size_t)4*NROWS*16*4); // quarter-major
  unsigned int* xbuf = (unsigned int*)alloc((size_t)4*NROWS*16*4); // quarter-major
  unsigned int* Wb0  = (unsigned int*)alloc((size_t)DIM*64*4);
  unsigned int* Wb1  = (unsigned int*)alloc((size_t)DIM*64*4);
  unsigned int* Wb2  = (unsigned int*)alloc((size_t)DIM*64*4);
  float* gq    = (float*)alloc((size_t)4*N_NODES*4);
  float* hgp   = (float*)alloc((size_t)3*POOL_BLKS*DIM*4);
  float* ssum  = (float*)alloc((size_t)3*N_GRAPHS*4);
  int*   gs    = (int*)alloc((size_t)(N_GRAPHS+1)*4);
  int*   cnt   = (int*)alloc((size_t)N_NODES*4);
  int*   srcb  = (int*)alloc(((size_t)N_NODES*CAP + 64)*4);

  const int T = 256;
  zero_misc     <<<(N_NODES+128+T-1)/T, T, 0, stream>>>(cnt, xw, xbuf);
  scatter_sliced<<<NCHUNK*NSLICE, T, 0, stream>>>(ei, cnt, srcb);
  prep          <<<196 + 96, T, 0, stream>>>(cnt, dis, batch, gs,
                                             w0, w1, w2, Wb0, Wb1, Wb2);

  // L0 GEMM (f32 input)
  gemm_f32<<<GEMM_BLKS, 256, 0, stream>>>(x, (const unsigned short*)Wb0, b0,
                                          dis, (unsigned short*)xw, GEMM_BLKS*4);
  // L0 aggregate (4 quarters in one launch, XCD-pair pinned)
  aggregate_q<<<AGG_BLKS*8, 256, 0, stream>>>((const uint4*)xw, cnt, srcb, dis,
                                              (uint4*)xbuf, gw, gq);
  // pool(L0) || gemm(L1)
  pool_gemm<<<GEMM_BLKS + POOL_BLKS, 256, 0, stream>>>(
      xbuf, gq, gb, gs, hgp, ssum,
      (const unsigned short*)Wb1, b1, dis, (unsigned short*)xw);
  // L1 aggregate
  aggregate_q<<<AGG_BLKS*8, 256, 0, stream>>>((const uint4*)xw, cnt, srcb, dis,
                                              (uint4*)xbuf, gw, gq);
  // pool(L1) || gemm(L2)
  pool_gemm<<<GEMM_BLKS + POOL_BLKS, 256, 0, stream>>>(
      xbuf, gq, gb, gs, hgp + (size_t)POOL_BLKS*DIM, ssum + N_GRAPHS,
      (const unsigned short*)Wb2, b2, dis, (unsigned short*)xw);
  // L2 aggregate
  aggregate_q<<<AGG_BLKS*8, 256, 0, stream>>>((const uint4*)xw, cnt, srcb, dis,
                                              (uint4*)xbuf, gw, gq);
  // pool(L2)
  att_pool<<<POOL_BLKS, 256, 0, stream>>>(xbuf, gq, gb, gs,
                                          hgp + (size_t)2*POOL_BLKS*DIM,
                                          ssum + 2*N_GRAPHS);
  head<<<N_GRAPHS, 256, 0, stream>>>(hgp, ssum, lw, lb, cw, cb, out);
}

// Round 13
// 201.176 us; speedup vs baseline: 1.0650x; 1.0650x over previous
//
#include <hip/hip_runtime.h>
#include <hip/hip_bf16.h>
#include <float.h>

#define N_NODES  50000
#define N_EDGES  640000
#define N_GRAPHS 128
#define DIM      128
#define CAP      64        // bucket slots per node; P(deg>=64) ~ 1e-24 per node
#define ZROW     N_NODES   // index of the all-zero row in xw/xbuf
#define NSLICE   8
#define SLICE_W  6250
#define NCHUNK   256
#define CHUNK_E  2500
#define GEMM_BLKS 512
#define POOL_BLKS 1024     // 8 per graph

typedef __attribute__((ext_vector_type(8))) short bf16x8;
typedef __attribute__((ext_vector_type(4))) float f32x4;

__device__ __forceinline__ unsigned short f2bf(float f){
  unsigned int u = __float_as_uint(f);
  u += 0x7fffu + ((u >> 16) & 1u);     // round-to-nearest-even
  return (unsigned short)(u >> 16);
}
__device__ __forceinline__ float2 up2(unsigned int p){
  return make_float2(__uint_as_float(p << 16),
                     __uint_as_float(p & 0xffff0000u));
}

// zero cnt + the two zero-rows (xw, xbuf)
__global__ __launch_bounds__(256) void zero_misc(int* __restrict__ cnt,
    unsigned int* __restrict__ z0, unsigned int* __restrict__ z1){
  int i = blockIdx.x*256 + threadIdx.x;
  if (i < N_NODES) cnt[i] = 0;
  else if (i < N_NODES + 64) z0[i - N_NODES] = 0;
  else if (i < N_NODES + 128) z1[i - N_NODES - 64] = 0;
}

// XCD-sliced scatter (L2-locality heuristic only; correctness order-free)
__global__ __launch_bounds__(256) void scatter_sliced(
    const int* __restrict__ ei, int* __restrict__ cnt, int* __restrict__ srcb){
  int slice = blockIdx.x & (NSLICE-1);
  int chunk = blockIdx.x >> 3;
  int e0 = chunk * CHUNK_E;
  for (int e = e0 + threadIdx.x; e < e0 + CHUNK_E; e += 256){
    int c = ei[N_EDGES + e];
    if (c / SLICE_W == slice){
      int r = ei[e];
      int pos = atomicAdd(&cnt[c], 1);
      srcb[(c << 6) + pos] = r;
    }
  }
}

// merged: make_dis + graph_starts + w3_to_bf16
__global__ __launch_bounds__(256) void prep(
    const int* __restrict__ cnt, float* __restrict__ dis,
    const int* __restrict__ batch, int* __restrict__ gs,
    const float* __restrict__ w0, const float* __restrict__ w1,
    const float* __restrict__ w2, unsigned int* __restrict__ o0,
    unsigned int* __restrict__ o1, unsigned int* __restrict__ o2){
  int b = blockIdx.x, tid = threadIdx.x;
  if (b < 196){
    int i = b*256 + tid;
    if (i < N_NODES){
      dis[i] = 1.0f / sqrtf((float)(cnt[i] + 1));
      int bb = batch[i];
      int bp = (i == 0) ? -1 : batch[i-1];
      for (int g = bp + 1; g <= bb; ++g) gs[g] = i;
      if (i == N_NODES - 1)
        for (int g = bb + 1; g <= N_GRAPHS; ++g) gs[g] = N_NODES;
    }
  } else {
    int i = (b - 196)*256 + tid;
    if (i < 3*8192){
      int a = i >> 13, j = i & 8191;
      const float* src = (a == 0) ? w0 : (a == 1) ? w1 : w2;
      unsigned int* dst = (a == 0) ? o0 : (a == 1) ? o1 : o2;
      float2 v = ((const float2*)src)[j];
      dst[j] = (unsigned int)f2bf(v.x) | ((unsigned int)f2bf(v.y) << 16);
    }
  }
}

// ---- GEMM body (bf16 input), dis-scaled epilogue ----
__device__ __forceinline__ void gemm_body_bf(int wid,
    const unsigned short* __restrict__ A, const unsigned short* __restrict__ Wb,
    const float* __restrict__ bias, const float* __restrict__ dis,
    unsigned short* __restrict__ C, int total_waves){
  int lane = threadIdx.x & 63;
  int l15 = lane & 15, l4 = lane >> 4;
  bf16x8 wf[8][4];
  #pragma unroll
  for (int ob = 0; ob < 8; ++ob)
    #pragma unroll
    for (int ks = 0; ks < 4; ++ks)
      wf[ob][ks] = *(const bf16x8*)&Wb[(ob*16 + l15)*128 + ks*32 + l4*8];
  float bv[8];
  #pragma unroll
  for (int ob = 0; ob < 8; ++ob) bv[ob] = bias[ob*16 + l15];
  for (int t = wid; t < N_NODES/16; t += total_waves){
    int row0 = t*16;
    bf16x8 af[4];
    #pragma unroll
    for (int ks = 0; ks < 4; ++ks)
      af[ks] = *(const bf16x8*)&A[(size_t)(row0 + l15)*128 + ks*32 + l4*8];
    f32x4 acc[8];
    #pragma unroll
    for (int ob = 0; ob < 8; ++ob) acc[ob] = (f32x4){0.f,0.f,0.f,0.f};
    #pragma unroll
    for (int ks = 0; ks < 4; ++ks)
      #pragma unroll
      for (int ob = 0; ob < 8; ++ob)
        acc[ob] = __builtin_amdgcn_mfma_f32_16x16x32_bf16(af[ks], wf[ob][ks],
                                                          acc[ob], 0, 0, 0);
    float dv[4];
    #pragma unroll
    for (int r = 0; r < 4; ++r) dv[r] = dis[row0 + l4*4 + r];
    #pragma unroll
    for (int ob = 0; ob < 8; ++ob)
      #pragma unroll
      for (int r = 0; r < 4; ++r)
        C[(size_t)(row0 + l4*4 + r)*128 + ob*16 + l15] =
            f2bf((acc[ob][r] + bv[ob]) * dv[r]);
  }
}

// layer-0 GEMM: f32 input, in-register RNE to bf16
__global__ __launch_bounds__(256, 2) void gemm_f32(
    const float* __restrict__ A, const unsigned short* __restrict__ Wb,
    const float* __restrict__ bias, const float* __restrict__ dis,
    unsigned short* __restrict__ C, int total_waves){
  int lane = threadIdx.x & 63;
  int wid = blockIdx.x*4 + (threadIdx.x >> 6);
  int l15 = lane & 15, l4 = lane >> 4;
  bf16x8 wf[8][4];
  #pragma unroll
  for (int ob = 0; ob < 8; ++ob)
    #pragma unroll
    for (int ks = 0; ks < 4; ++ks)
      wf[ob][ks] = *(const bf16x8*)&Wb[(ob*16 + l15)*128 + ks*32 + l4*8];
  float bv[8];
  #pragma unroll
  for (int ob = 0; ob < 8; ++ob) bv[ob] = bias[ob*16 + l15];
  for (int t = wid; t < N_NODES/16; t += total_waves){
    int row0 = t*16;
    bf16x8 af[4];
    #pragma unroll
    for (int ks = 0; ks < 4; ++ks){
      const float4* ap = (const float4*)&A[(size_t)(row0 + l15)*128 + ks*32 + l4*8];
      float4 fa = ap[0], fb = ap[1];
      bf16x8 v;
      v[0]=(short)f2bf(fa.x); v[1]=(short)f2bf(fa.y);
      v[2]=(short)f2bf(fa.z); v[3]=(short)f2bf(fa.w);
      v[4]=(short)f2bf(fb.x); v[5]=(short)f2bf(fb.y);
      v[6]=(short)f2bf(fb.z); v[7]=(short)f2bf(fb.w);
      af[ks] = v;
    }
    f32x4 acc[8];
    #pragma unroll
    for (int ob = 0; ob < 8; ++ob) acc[ob] = (f32x4){0.f,0.f,0.f,0.f};
    #pragma unroll
    for (int ks = 0; ks < 4; ++ks)
      #pragma unroll
      for (int ob = 0; ob < 8; ++ob)
        acc[ob] = __builtin_amdgcn_mfma_f32_16x16x32_bf16(af[ks], wf[ob][ks],
                                                          acc[ob], 0, 0, 0);
    float dv[4];
    #pragma unroll
    for (int r = 0; r < 4; ++r) dv[r] = dis[row0 + l4*4 + r];
    #pragma unroll
    for (int ob = 0; ob < 8; ++ob)
      #pragma unroll
      for (int r = 0; r < 4; ++r)
        C[(size_t)(row0 + l4*4 + r)*128 + ob*16 + l15] =
            f2bf((acc[ob][r] + bv[ob]) * dv[r]);
  }
}

// ---- pooling body: redundant per-block max/sum; q==0 writes ssum ----
__device__ __forceinline__ void pool_body(int pbid,
    const unsigned int* __restrict__ x, const float* __restrict__ gate,
    const int* __restrict__ gs, float* __restrict__ hgp,
    float* __restrict__ ssum){
  int g = pbid >> 3, q = pbid & 7, tid = threadIdx.x;
  int s = gs[g], e = gs[g+1];
  __shared__ float red[256];
  __shared__ float2 red2[4][64];
  float m = -FLT_MAX;
  for (int i = s + tid; i < e; i += 256) m = fmaxf(m, gate[i]);
  red[tid] = m; __syncthreads();
  for (int st = 128; st > 0; st >>= 1){
    if (tid < st) red[tid] = fmaxf(red[tid], red[tid+st]);
    __syncthreads();
  }
  m = red[0]; __syncthreads();
  float p = 0.f;
  for (int i = s + tid; i < e; i += 256) p += __expf(gate[i] - m);
  red[tid] = p; __syncthreads();
  for (int st = 128; st > 0; st >>= 1){
    if (tid < st) red[tid] += red[tid+st];
    __syncthreads();
  }
  if (tid == 0 && q == 0) ssum[g] = red[0];
  int d2 = tid & 63, rg = tid >> 6;
  float ax = 0.f, ay = 0.f;
  for (int i = s + q*4 + rg; i < e; i += 32){
    float a = __expf(gate[i] - m);
    float2 u = up2(x[(size_t)i*64 + d2]);
    ax += a*u.x; ay += a*u.y;
  }
  red2[rg][d2] = make_float2(ax, ay);
  __syncthreads();
  if (tid < 64){
    float2 r0 = red2[0][tid], r1 = red2[1][tid],
           r2 = red2[2][tid], r3 = red2[3][tid];
    hgp[(size_t)pbid*128 + 2*tid    ] = r0.x + r1.x + r2.x + r3.x;
    hgp[(size_t)pbid*128 + 2*tid + 1] = r0.y + r1.y + r2.y + r3.y;
  }
}

// fused: blocks [0,GEMM_BLKS) = next-layer GEMM; rest = this-layer pooling.
// Both only READ xb; outputs disjoint (xwout vs hgp/ssum). No sync needed.
__global__ __launch_bounds__(256, 2) void pool_gemm(
    const unsigned int* __restrict__ xb, const float* __restrict__ gate,
    const int* __restrict__ gs, float* __restrict__ hgp,
    float* __restrict__ ssum,
    const unsigned short* __restrict__ Wb, const float* __restrict__ bias,
    const float* __restrict__ dis, unsigned short* __restrict__ xwout){
  if (blockIdx.x < GEMM_BLKS){
    int wid = blockIdx.x*4 + (threadIdx.x >> 6);
    gemm_body_bf(wid, (const unsigned short*)xb, Wb, bias, dis, xwout,
                 GEMM_BLKS*4);
  } else {
    pool_body(blockIdx.x - GEMM_BLKS, xb, gate, gs, hgp, ssum);
  }
}

// standalone pooling (last layer)
__global__ __launch_bounds__(256) void att_pool(
    const unsigned int* __restrict__ xb, const float* __restrict__ gate,
    const int* __restrict__ gs, float* __restrict__ hgp,
    float* __restrict__ ssum){
  pool_body(blockIdx.x, xb, gate, gs, hgp, ssum);
}

// rows pre-scaled by dis[r]: out[c] = relu(dis[c]*(xw_s[c] + sum_in xw_s[r]))
// 4 parity waves per node-quad (stride 32), 16 lanes/node, 8-deep uint4 gathers.
__global__ __launch_bounds__(256) void aggregate_bf(
    const uint4* __restrict__ xw4,
    const int* __restrict__ cnt, const int* __restrict__ srcb,
    const float* __restrict__ dis,
    uint4* __restrict__ xout4, const float* __restrict__ gw,
    const float* __restrict__ gb, float* __restrict__ gate){
  int tid  = threadIdx.x;
  int lane = tid & 63;
  int par  = tid >> 6;           // 0..3 (edge-parity wave)
  int sub  = lane >> 4, l16 = lane & 15;
  int node = blockIdx.x*4 + sub; // grid = N_NODES/4, exact
  int   n  = cnt[node];
  int base = node << 6;
  float acc[8];
  #pragma unroll
  for (int i = 0; i < 8; ++i) acc[i] = 0.f;
  if (par == 0){
    uint4 v = xw4[node*16 + l16];
    float2 a0 = up2(v.x), a1 = up2(v.y), a2 = up2(v.z), a3 = up2(v.w);
    acc[0]=a0.x; acc[1]=a0.y; acc[2]=a1.x; acc[3]=a1.y;
    acc[4]=a2.x; acc[5]=a2.y; acc[6]=a3.x; acc[7]=a3.y;
  }
  for (int e = par*8; e < n; e += 32){
    int4 sa = *(const int4*)&srcb[base + e];
    int4 sb = *(const int4*)&srcb[base + e + 4];
    int r0 = (e   < n) ? sa.x : ZROW;
    int r1 = (e+1 < n) ? sa.y : ZROW;
    int r2 = (e+2 < n) ? sa.z : ZROW;
    int r3 = (e+3 < n) ? sa.w : ZROW;
    int r4 = (e+4 < n) ? sb.x : ZROW;
    int r5 = (e+5 < n) ? sb.y : ZROW;
    int r6 = (e+6 < n) ? sb.z : ZROW;
    int r7 = (e+7 < n) ? sb.w : ZROW;
    uint4 u0 = xw4[r0*16 + l16];
    uint4 u1 = xw4[r1*16 + l16];
    uint4 u2 = xw4[r2*16 + l16];
    uint4 u3 = xw4[r3*16 + l16];
    uint4 u4 = xw4[r4*16 + l16];
    uint4 u5 = xw4[r5*16 + l16];
    uint4 u6 = xw4[r6*16 + l16];
    uint4 u7 = xw4[r7*16 + l16];
    #define ACC8(U) { \
      float2 b0=up2(U.x), b1=up2(U.y), b2=up2(U.z), b3=up2(U.w); \
      acc[0]+=b0.x; acc[1]+=b0.y; acc[2]+=b1.x; acc[3]+=b1.y;    \
      acc[4]+=b2.x; acc[5]+=b2.y; acc[6]+=b3.x; acc[7]+=b3.y; }
    ACC8(u0) ACC8(u1) ACC8(u2) ACC8(u3)
    ACC8(u4) ACC8(u5) ACC8(u6) ACC8(u7)
    #undef ACC8
  }
  __shared__ float comb[3][64][9];   // partials from par 1..3
  if (par > 0){
    #pragma unroll
    for (int i = 0; i < 8; ++i) comb[par-1][lane][i] = acc[i];
  }
  __syncthreads();
  if (par == 0){
    float d = dis[node];
    #pragma unroll
    for (int i = 0; i < 8; ++i)
      acc[i] = fmaxf(d*(acc[i] + comb[0][lane][i] + comb[1][lane][i]
                               + comb[2][lane][i]), 0.f);
    uint4 o;
    o.x = (unsigned int)f2bf(acc[0]) | ((unsigned int)f2bf(acc[1]) << 16);
    o.y = (unsigned int)f2bf(acc[2]) | ((unsigned int)f2bf(acc[3]) << 16);
    o.z = (unsigned int)f2bf(acc[4]) | ((unsigned int)f2bf(acc[5]) << 16);
    o.w = (unsigned int)f2bf(acc[6]) | ((unsigned int)f2bf(acc[7]) << 16);
    xout4[node*16 + l16] = o;
    const float4* gw4 = (const float4*)gw;
    float4 g0 = gw4[l16*2], g1 = gw4[l16*2 + 1];
    float p = acc[0]*g0.x + acc[1]*g0.y + acc[2]*g0.z + acc[3]*g0.w
            + acc[4]*g1.x + acc[5]*g1.y + acc[6]*g1.z + acc[7]*g1.w;
    p += __shfl_xor(p, 1, 64);
    p += __shfl_xor(p, 2, 64);
    p += __shfl_xor(p, 4, 64);
    p += __shfl_xor(p, 8, 64);
    if (l16 == 0) gate[node] = p + gb[0];
  }
}

// hg[g] = sum_L (sum_q hgp[L][8g+q]) / ssum[L][g]; then MLP head
__global__ __launch_bounds__(256) void head(const float* __restrict__ hgp,
    const float* __restrict__ ssum,
    const float* __restrict__ lw, const float* __restrict__ lb,
    const float* __restrict__ cw, const float* __restrict__ cb,
    float* __restrict__ out){
  int g = blockIdx.x, tid = threadIdx.x;
  __shared__ float h[128];
  __shared__ float t1[256];
  __shared__ float red[256];
  if (tid < 128){
    float hv = 0.f;
    #pragma unroll
    for (int L = 0; L < 3; ++L){
      const float* hb = hgp + (size_t)(L*POOL_BLKS + 8*g)*128;
      float pp = 0.f;
      #pragma unroll
      for (int q = 0; q < 8; ++q) pp += hb[q*128 + tid];
      float sv = ssum[L*N_GRAPHS + g];
      hv += (sv > 0.f) ? pp/sv : 0.f;
    }
    h[tid] = hv;
  }
  __syncthreads();
  const float* wr = lw + tid*128;
  float a = 0.f;
  for (int k = 0; k < 128; ++k) a += h[k]*wr[k];
  a = fmaxf(a + lb[tid], 0.f);
  t1[tid] = a;
  __syncthreads();
  int o = tid >> 7, j = tid & 127;
  float p = t1[j]*cw[o*256 + j] + t1[j+128]*cw[o*256 + j + 128];
  red[tid] = p; __syncthreads();
  for (int st = 64; st > 0; st >>= 1){
    if (j < st) red[tid] += red[tid+st];
    __syncthreads();
  }
  if (j == 0) out[g*2 + o] = red[tid] + cb[o];
}

extern "C" void kernel_launch(void* const* d_in, const int* in_sizes, int n_in,
                              void* d_out, int out_size, void* d_ws, size_t ws_size,
                              hipStream_t stream){
  const float* x   = (const float*)d_in[0];
  const int*   ei  = (const int*)d_in[1];
  const int* batch = (const int*)d_in[2];
  const float* w0  = (const float*)d_in[3];
  const float* b0  = (const float*)d_in[4];
  const float* w1  = (const float*)d_in[5];
  const float* b1  = (const float*)d_in[6];
  const float* w2  = (const float*)d_in[7];
  const float* b2  = (const float*)d_in[8];
  const float* gw  = (const float*)d_in[9];
  const float* gb  = (const float*)d_in[10];
  const float* lw  = (const float*)d_in[11];
  const float* lb  = (const float*)d_in[12];
  const float* cw  = (const float*)d_in[13];
  const float* cb  = (const float*)d_in[14];
  float* out = (float*)d_out;
  (void)in_sizes; (void)n_in; (void)out_size; (void)ws_size;

  char* ws = (char*)d_ws;
  size_t off = 0;
  auto alloc = [&](size_t bytes)->char*{
    char* p = ws + off;
    off = (off + bytes + 255) & ~(size_t)255;
    return p;
  };
  float* dis    = (float*)alloc((size_t)N_NODES*4);
  unsigned int* xw   = (unsigned int*)alloc((size_t)(N_NODES+1)*64*4); // +zero row
  unsigned int* xbuf = (unsigned int*)alloc((size_t)(N_NODES+1)*64*4); // +zero row
  unsigned int* Wb0  = (unsigned int*)alloc((size_t)DIM*64*4);
  unsigned int* Wb1  = (unsigned int*)alloc((size_t)DIM*64*4);
  unsigned int* Wb2  = (unsigned int*)alloc((size_t)DIM*64*4);
  float* gate  = (float*)alloc((size_t)N_NODES*4);
  float* hgp   = (float*)alloc((size_t)3*POOL_BLKS*DIM*4);
  float* ssum  = (float*)alloc((size_t)3*N_GRAPHS*4);
  int*   gs    = (int*)alloc((size_t)(N_GRAPHS+1)*4);
  int*   cnt   = (int*)alloc((size_t)N_NODES*4);
  int*   srcb  = (int*)alloc(((size_t)N_NODES*CAP + 64)*4);

  const int T = 256;
  zero_misc     <<<(N_NODES+128+T-1)/T, T, 0, stream>>>(cnt,
                    xw + (size_t)ZROW*64, xbuf + (size_t)ZROW*64);
  scatter_sliced<<<NCHUNK*NSLICE, T, 0, stream>>>(ei, cnt, srcb);
  prep          <<<196 + 96, T, 0, stream>>>(cnt, dis, batch, gs,
                                             w0, w1, w2, Wb0, Wb1, Wb2);

  // L0 GEMM (f32 input)
  gemm_f32<<<GEMM_BLKS, 256, 0, stream>>>(x, (const unsigned short*)Wb0, b0,
                                          dis, (unsigned short*)xw, GEMM_BLKS*4);
  // L0 aggregate
  aggregate_bf<<<N_NODES/4, 256, 0, stream>>>((const uint4*)xw, cnt, srcb, dis,
                                              (uint4*)xbuf, gw, gb, gate);
  // pool(L0) || gemm(L1)
  pool_gemm<<<GEMM_BLKS + POOL_BLKS, 256, 0, stream>>>(
      xbuf, gate, gs, hgp, ssum,
      (const unsigned short*)Wb1, b1, dis, (unsigned short*)xw);
  // L1 aggregate
  aggregate_bf<<<N_NODES/4, 256, 0, stream>>>((const uint4*)xw, cnt, srcb, dis,
                                              (uint4*)xbuf, gw, gb, gate);
  // pool(L1) || gemm(L2)
  pool_gemm<<<GEMM_BLKS + POOL_BLKS, 256, 0, stream>>>(
      xbuf, gate, gs, hgp + (size_t)POOL_BLKS*DIM, ssum + N_GRAPHS,
      (const unsigned short*)Wb2, b2, dis, (unsigned short*)xw);
  // L2 aggregate
  aggregate_bf<<<N_NODES/4, 256, 0, stream>>>((const uint4*)xw, cnt, srcb, dis,
                                              (uint4*)xbuf, gw, gb, gate);
  // pool(L2)
  att_pool<<<POOL_BLKS, 256, 0, stream>>>(xbuf, gate, gs,
                                          hgp + (size_t)2*POOL_BLKS*DIM,
                                          ssum + 2*N_GRAPHS);
  head<<<N_GRAPHS, 256, 0, stream>>>(hgp, ssum, lw, lb, cw, cb, out);
}